// Round 1
// baseline (110.199 us; speedup 1.0000x reference)
//
#include <hip/hip_runtime.h>

// D=32, H=64, O=1, T=1024, M=8, N=32768, S=2177
//
// New structure (T << N  =>  materialize per-ticker weights, like the reference):
//   Phase A (state_kernel):  states[t][s] = base[s]+metab[s]+sum_m metaw[s][m]*mesa[m][t]
//       stored in d_ws as W1S[t][d][j] (transposed for coalesced j-reads), B1S[t][j],
//       W2S[t][j], B2S[t], plus ticker compressed to uint16 (halves scan traffic).
//   Phase E (apply_kernel): block = (t, half). lane = j. W1[t] lives in 32 VGPRs/lane.
//       Each wave scans 4096 tickers with __ballot; for each match n:
//       h[j] = relu(s_load(x[n]) . w1r + b1), out[n] = sum_j h*w2 + b2  (wave shfl reduce).
// FLOPs: 1.8e7 (A) + 6.9e7 (E) FMAs  vs  5.5e8 FMAs in the single-kernel basis version.

#define DD 32
#define TT 1024
#define MM 8
#define KB 8

// ---------------- Phase A: materialize per-ticker states ----------------
__global__ __launch_bounds__(256, 4) void state_kernel(
    const float* __restrict__ mesa,    // (8,1024)
    const float* __restrict__ metaw,   // (2177,8)
    const float* __restrict__ metab,   // (2177,)
    const float* __restrict__ base,    // (2177,)
    const int*   __restrict__ ticker,  // (32768,)
    float* __restrict__ ws)
{
    const int t    = blockIdx.x;        // one block per ticker value
    const int lane = threadIdx.x & 63;  // j
    const int w    = threadIdx.x >> 6;  // wave 0..3

    float* W1S = ws;                      // [1024][32][64]  (t, d, j)
    float* B1S = ws + TT * 2048;          // [1024][64]
    float* W2S = B1S + TT * 64;           // [1024][64]
    float* B2S = W2S + TT * 64;           // [1024]
    unsigned short* tick16 = (unsigned short*)(B2S + TT);   // [32768]

    float mm[8];
    #pragma unroll
    for (int m = 0; m < 8; ++m) mm[m] = mesa[m * TT + t];   // wave-uniform s_loads

    // each wave computes 8 d-planes; stores coalesced over j
    #pragma unroll
    for (int dd = 0; dd < 8; ++dd) {
        int d = w * 8 + dd;
        int s = lane * 32 + d;
        const float4 u0 = *(const float4*)(metaw + s * MM);
        const float4 u1 = *(const float4*)(metaw + s * MM + 4);
        float v = base[s] + metab[s]
                + mm[0]*u0.x + mm[1]*u0.y + mm[2]*u0.z + mm[3]*u0.w
                + mm[4]*u1.x + mm[5]*u1.y + mm[6]*u1.z + mm[7]*u1.w;
        W1S[t * 2048 + d * 64 + lane] = v;
    }

    if (w == 0) {                       // b1
        int s = 2048 + lane;
        const float4 u0 = *(const float4*)(metaw + s * MM);
        const float4 u1 = *(const float4*)(metaw + s * MM + 4);
        B1S[t * 64 + lane] = base[s] + metab[s]
                + mm[0]*u0.x + mm[1]*u0.y + mm[2]*u0.z + mm[3]*u0.w
                + mm[4]*u1.x + mm[5]*u1.y + mm[6]*u1.z + mm[7]*u1.w;
    } else if (w == 1) {                // w2
        int s = 2112 + lane;
        const float4 u0 = *(const float4*)(metaw + s * MM);
        const float4 u1 = *(const float4*)(metaw + s * MM + 4);
        W2S[t * 64 + lane] = base[s] + metab[s]
                + mm[0]*u0.x + mm[1]*u0.y + mm[2]*u0.z + mm[3]*u0.w
                + mm[4]*u1.x + mm[5]*u1.y + mm[6]*u1.z + mm[7]*u1.w;
    } else if (w == 2) {                // b2 (scalar)
        if (lane == 0) {
            const float4 u0 = *(const float4*)(metaw + 2176 * MM);
            const float4 u1 = *(const float4*)(metaw + 2176 * MM + 4);
            B2S[t] = base[2176] + metab[2176]
                + mm[0]*u0.x + mm[1]*u0.y + mm[2]*u0.z + mm[3]*u0.w
                + mm[4]*u1.x + mm[5]*u1.y + mm[6]*u1.z + mm[7]*u1.w;
        }
    } else {                            // compress ticker slice [t*32, t*32+32)
        if (lane < 32) tick16[t * 32 + lane] = (unsigned short)ticker[t * 32 + lane];
    }
}

// ---------------- Phase E: per-sample apply with per-ticker blocks ----------------
__global__ __launch_bounds__(256, 8) void apply_kernel(
    const float* __restrict__ x,      // (32768,32)
    const float* __restrict__ ws,
    float* __restrict__ out)          // (32768,1)
{
    const int lane = threadIdx.x & 63;   // j
    const int w    = threadIdx.x >> 6;   // wave 0..3
    const int t    = blockIdx.x >> 1;    // ticker owned by this block
    const int half = blockIdx.x & 1;     // which half of the sample range we scan

    const float* W1S = ws;
    const float* B1S = ws + TT * 2048;
    const float* W2S = B1S + TT * 64;
    const float* B2S = W2S + TT * 64;
    const unsigned short* tick16 = (const unsigned short*)(B2S + TT);

    // this block's weights: lane j holds w1[t][j][0..31] (reads coalesced over j)
    float w1r[32];
    #pragma unroll
    for (int d = 0; d < 32; ++d) w1r[d] = W1S[t * 2048 + d * 64 + lane];
    const float b1r = B1S[t * 64 + lane];
    const float w2r = W2S[t * 64 + lane];
    const float b2v = B2S[t];

    const unsigned short tu = (unsigned short)t;
    const int base0 = half * 16384 + w * 4096;   // wave-private scan range

    for (int c = 0; c < 4096; c += 64) {
        int n = base0 + c + lane;
        unsigned long long m = __ballot(tick16[n] == tu);
        while (m) {
            int b = __ffsll(m) - 1;
            m &= (m - 1);
            int nn = base0 + c + b;                    // wave-uniform (SGPR)
            const float* xp = x + (nn << 5);           // uniform -> scalar loads
            float a0 = 0.f, a1 = 0.f, a2 = 0.f, a3 = 0.f;
            #pragma unroll
            for (int d = 0; d < 32; d += 4) {
                a0 = fmaf(xp[d + 0], w1r[d + 0], a0);
                a1 = fmaf(xp[d + 1], w1r[d + 1], a1);
                a2 = fmaf(xp[d + 2], w1r[d + 2], a2);
                a3 = fmaf(xp[d + 3], w1r[d + 3], a3);
            }
            float h = fmaxf((a0 + a1) + (a2 + a3) + b1r, 0.f) * w2r;
            #pragma unroll
            for (int off = 32; off >= 1; off >>= 1)
                h += __shfl_down(h, off, 64);
            if (lane == 0) out[nn] = h + b2v;
        }
    }
}

// ---------------- Fallback: previous best single-kernel version ----------------
__global__ __launch_bounds__(1024, 4) void fused_kernel(
    const float* __restrict__ x,
    const int*   __restrict__ ticker,
    const float* __restrict__ mesa,
    const float* __restrict__ metaw,
    const float* __restrict__ metab,
    const float* __restrict__ base,
    float* __restrict__ out)
{
    __shared__ float4 U4[32 * 2 * 64];
    __shared__ float4 B1q[8 * 64];
    __shared__ float4 Ub1[2 * 64];
    __shared__ float4 U2q[2 * 64];
    __shared__ float  B1b[64];
    __shared__ float  B2b[64];

    const int tid  = threadIdx.x;
    const int lane = tid & 63;
    const int dm   = tid >> 6;

    #pragma unroll
    for (int i2 = 0; i2 < 4; ++i2) {
        int idx = dm * 4 + i2;
        int d = idx >> 1, m4 = idx & 1;
        U4[(d * 2 + m4) * 64 + lane] =
            *(const float4*)(metaw + ((lane * 32 + d) * MM + m4 * 4));
    }
    if (dm < 8) {
        int s0 = lane * 32 + dm * 4;
        float4 bv = *(const float4*)(base  + s0);
        float4 mv = *(const float4*)(metab + s0);
        B1q[dm * 64 + lane] = make_float4(bv.x + mv.x, bv.y + mv.y, bv.z + mv.z, bv.w + mv.w);
    } else if (dm < 10) {
        int m4 = dm - 8;
        Ub1[m4 * 64 + lane] = *(const float4*)(metaw + ((2048 + lane) * MM + m4 * 4));
    } else if (dm < 12) {
        int m4 = dm - 10;
        U2q[m4 * 64 + lane] = *(const float4*)(metaw + ((2112 + lane) * MM + m4 * 4));
    } else if (dm == 12) {
        B1b[lane] = base[2048 + lane] + metab[2048 + lane];
    } else if (dm == 13) {
        B2b[lane] = base[2112 + lane] + metab[2112 + lane];
    }
    __syncthreads();

    const int n0 = blockIdx.x * 128 + dm * KB;

    float xr[4];
    #pragma unroll
    for (int r = 0; r < 4; ++r) xr[r] = x[n0 * DD + r * 64 + lane];

    float4 g0[KB], g1[KB];
    float  c0[KB];
    #pragma unroll
    for (int i = 0; i < KB; ++i) {
        g0[i] = make_float4(0.f, 0.f, 0.f, 0.f);
        g1[i] = make_float4(0.f, 0.f, 0.f, 0.f);
        c0[i] = 0.f;
    }

    for (int dq = 0; dq < 8; ++dq) {
        float4 bq = B1q[dq * 64 + lane];
        #pragma unroll
        for (int dd = 0; dd < 4; ++dd) {
            int d = dq * 4 + dd;
            float4 u0 = U4[(d * 2 + 0) * 64 + lane];
            float4 u1 = U4[(d * 2 + 1) * 64 + lane];
            float bs = (dd == 0) ? bq.x : (dd == 1) ? bq.y : (dd == 2) ? bq.z : bq.w;
            #pragma unroll
            for (int i = 0; i < KB; ++i) {
                int lidx = (i & 1) * 32 + d;
                float xv = __uint_as_float(
                    __builtin_amdgcn_readlane(__float_as_uint(xr[i >> 1]), lidx));
                c0[i]   = fmaf(xv, bs,   c0[i]);
                g0[i].x = fmaf(xv, u0.x, g0[i].x);
                g0[i].y = fmaf(xv, u0.y, g0[i].y);
                g0[i].z = fmaf(xv, u0.z, g0[i].z);
                g0[i].w = fmaf(xv, u0.w, g0[i].w);
                g1[i].x = fmaf(xv, u1.x, g1[i].x);
                g1[i].y = fmaf(xv, u1.y, g1[i].y);
                g1[i].z = fmaf(xv, u1.z, g1[i].z);
                g1[i].w = fmaf(xv, u1.w, g1[i].w);
            }
        }
    }

    float4 ub1a = Ub1[0 * 64 + lane], ub1b = Ub1[1 * 64 + lane];
    float4 u2a  = U2q[0 * 64 + lane], u2b  = U2q[1 * 64 + lane];
    float  b1base = B1b[lane], b2base = B2b[lane];
    float4 w2m0 = *(const float4*)(metaw + 2176 * MM);
    float4 w2m1 = *(const float4*)(metaw + 2176 * MM + 4);
    float  b2c  = base[2176] + metab[2176];

    #pragma unroll
    for (int i = 0; i < KB; ++i) {
        int n = n0 + i;
        int t = ticker[n];
        float mi[8];
        #pragma unroll
        for (int m = 0; m < 8; ++m) mi[m] = mesa[m * TT + t];

        float b1 = b1base
                 + mi[0] * ub1a.x + mi[1] * ub1a.y + mi[2] * ub1a.z + mi[3] * ub1a.w
                 + mi[4] * ub1b.x + mi[5] * ub1b.y + mi[6] * ub1b.z + mi[7] * ub1b.w;
        float h = c0[i] + b1
                 + mi[0] * g0[i].x + mi[1] * g0[i].y + mi[2] * g0[i].z + mi[3] * g0[i].w
                 + mi[4] * g1[i].x + mi[5] * g1[i].y + mi[6] * g1[i].z + mi[7] * g1[i].w;
        h = fmaxf(h, 0.f);
        float w2 = b2base
                 + mi[0] * u2a.x + mi[1] * u2a.y + mi[2] * u2a.z + mi[3] * u2a.w
                 + mi[4] * u2b.x + mi[5] * u2b.y + mi[6] * u2b.z + mi[7] * u2b.w;
        float p = h * w2;
        #pragma unroll
        for (int off = 32; off >= 1; off >>= 1)
            p += __shfl_down(p, off, 64);
        if (lane == 0) {
            float b2 = b2c
                 + mi[0] * w2m0.x + mi[1] * w2m0.y + mi[2] * w2m0.z + mi[3] * w2m0.w
                 + mi[4] * w2m1.x + mi[5] * w2m1.y + mi[6] * w2m1.z + mi[7] * w2m1.w;
            out[n] = p + b2;
        }
    }
}

extern "C" void kernel_launch(void* const* d_in, const int* in_sizes, int n_in,
                              void* d_out, int out_size, void* d_ws, size_t ws_size,
                              hipStream_t stream) {
    const float* x      = (const float*)d_in[0];
    const int*   ticker = (const int*)  d_in[1];
    const float* mesa   = (const float*)d_in[2];
    const float* metaw  = (const float*)d_in[3];
    const float* metab  = (const float*)d_in[4];
    const float* base   = (const float*)d_in[5];
    float* out = (float*)d_out;

    // ws layout: W1S (8 MB) + B1S (256 KB) + W2S (256 KB) + B2S (4 KB) + tick16 (64 KB)
    const size_t need = (size_t)(TT * 2048 + TT * 64 + TT * 64 + TT) * sizeof(float)
                      + (size_t)32768 * sizeof(unsigned short);

    if (ws_size >= need) {
        state_kernel<<<TT, 256, 0, stream>>>(mesa, metaw, metab, base, ticker, (float*)d_ws);
        apply_kernel<<<2 * TT, 256, 0, stream>>>(x, (const float*)d_ws, out);
    } else {
        fused_kernel<<<256, 1024, 0, stream>>>(x, ticker, mesa, metaw, metab, base, out);
    }
}

// Round 2
// 91.074 us; speedup vs baseline: 1.2100x; 1.2100x over previous
//
#include <hip/hip_runtime.h>

// D=32, H=64, O=1, T=1024, M=8, N=32768, S=2177
//
// Single-kernel "ticker-owner" design (no d_ws => no 256MiB re-poison fill in
// the timed graph):
//   Block t (1024 blocks, 512 thr) computes states[t][s] = base[s]+metab[s]
//     + sum_m metaw[s][m]*mesa[m][t] for all s into padded LDS (9 KB).
//   Its 8 waves then scan the ticker array (wave w owns samples
//   [w*4096,(w+1)*4096)) via int4 loads + __ballot. For each match n:
//     h[j] = relu(x[n].w1[t][j] + b1[t][j])  (lane = j, w1 row read from LDS,
//     j*33 padding -> conflict-free), out[n] = sum_j h*w2 + b2 via shfl reduce.
// FLOPs: 1.8e7 (stage) + 2.1e3/sample * 32768 (apply) ~ 8.7e7 FMAs total,
// vs 5.5e8 in the old basis kernel. Scan traffic: 1024 blocks * 128 KB = 134 MB
// (L2-resident). Exactly one block-wave matches each n => one writer per out[n].

#define TT 1024

__device__ __forceinline__ int pidx(int s) { return s + (s >> 5); }  // pad 1/32

__global__ __launch_bounds__(512, 8) void fused_owner_kernel(
    const float* __restrict__ x,       // (32768,32)
    const int*   __restrict__ ticker,  // (32768,)
    const float* __restrict__ mesa,    // (8,1024)
    const float* __restrict__ metaw,   // (2177,8)
    const float* __restrict__ metab,   // (2177,)
    const float* __restrict__ base,    // (2177,)
    float* __restrict__ out)           // (32768,1)
{
    __shared__ float sm[2304];           // padded states; max idx = 2176+68 = 2244.. (rounded)

    const int t    = blockIdx.x;         // this block's ticker value
    const int tid  = threadIdx.x;
    const int lane = tid & 63;           // j (hidden unit)
    const int w    = tid >> 6;           // wave 0..7

    // mesa coefficients for this t (block-uniform -> scalar loads)
    float mm[8];
    #pragma unroll
    for (int m = 0; m < 8; ++m) mm[m] = mesa[m * TT + t];

    // ---- stage: all 2177 states for ticker t into padded LDS (coalesced) ----
    #pragma unroll
    for (int k = 0; k < 5; ++k) {
        int s = tid + k * 512;
        if (s < 2177) {
            const float4 u0 = *(const float4*)(metaw + s * 8);
            const float4 u1 = *(const float4*)(metaw + s * 8 + 4);
            float v = base[s] + metab[s]
                    + mm[0]*u0.x + mm[1]*u0.y + mm[2]*u0.z + mm[3]*u0.w
                    + mm[4]*u1.x + mm[5]*u1.y + mm[6]*u1.z + mm[7]*u1.w;
            sm[pidx(s)] = v;
        }
    }
    __syncthreads();

    // per-lane epilogue params (2-way bank aliasing at worst = free)
    const int   jb  = lane * 33;           // LDS index of w1[t][j][0]
    const float b1r = sm[pidx(2048 + lane)];
    const float w2r = sm[pidx(2112 + lane)];
    const float b2v = sm[pidx(2176)];      // broadcast

    // ---- scan this wave's 4096-sample slice ----
    const int   nbase = w * 4096;
    const int4* tick4 = (const int4*)ticker + (nbase >> 2);

    #pragma unroll 2
    for (int c = 0; c < 4096; c += 256) {
        const int4 tv = tick4[(c >> 2) + lane];   // samples nbase+c+lane*4 ..+3
        unsigned long long m0 = __ballot(tv.x == t);
        unsigned long long m1 = __ballot(tv.y == t);
        unsigned long long m2 = __ballot(tv.z == t);
        unsigned long long m3 = __ballot(tv.w == t);

        #pragma unroll
        for (int comp = 0; comp < 4; ++comp) {
            unsigned long long m = (comp == 0) ? m0 : (comp == 1) ? m1
                                 : (comp == 2) ? m2 : m3;
            while (m) {                              // wave-uniform loop
                const int b = __ffsll(m) - 1;
                m &= (m - 1);
                const int nn = nbase + c + b * 4 + comp;   // uniform (SGPR)
                const float* xp = x + (nn << 5);

                float a0 = 0.f, a1 = 0.f, a2 = 0.f, a3 = 0.f;
                #pragma unroll
                for (int q = 0; q < 8; ++q) {
                    const float4 xv = *(const float4*)(xp + q * 4);  // broadcast
                    a0 = fmaf(xv.x, sm[jb + q * 4 + 0], a0);
                    a1 = fmaf(xv.y, sm[jb + q * 4 + 1], a1);
                    a2 = fmaf(xv.z, sm[jb + q * 4 + 2], a2);
                    a3 = fmaf(xv.w, sm[jb + q * 4 + 3], a3);
                }
                float h = fmaxf((a0 + a1) + (a2 + a3) + b1r, 0.f) * w2r;
                #pragma unroll
                for (int off = 32; off >= 1; off >>= 1)
                    h += __shfl_down(h, off, 64);
                if (lane == 0) out[nn] = h + b2v;
            }
        }
    }
}

extern "C" void kernel_launch(void* const* d_in, const int* in_sizes, int n_in,
                              void* d_out, int out_size, void* d_ws, size_t ws_size,
                              hipStream_t stream) {
    const float* x      = (const float*)d_in[0];
    const int*   ticker = (const int*)  d_in[1];
    const float* mesa   = (const float*)d_in[2];
    const float* metaw  = (const float*)d_in[3];
    const float* metab  = (const float*)d_in[4];
    const float* base   = (const float*)d_in[5];
    float* out = (float*)d_out;

    // 1024 blocks (one per ticker value) x 512 threads; d_ws deliberately unused.
    fused_owner_kernel<<<TT, 512, 0, stream>>>(x, ticker, mesa, metaw, metab, base, out);
}